// Round 1
// 65.242 us; speedup vs baseline: 1.0046x; 1.0046x over previous
//
#include <hip/hip_runtime.h>

// QConv2D quanvolution — single fused kernel, parallel setup, Horner eval (R9).
// Heisenberg picture: z_w(patch) = sum_{P in {I,Y,Z}^4} c_{w,P} * prod_q t_q(P_q),
//   t(I)=1, t(Y)=-sin a_q, t(Z)=cos a_q;  c_{w,P} fixed by params.
// R9 change: occupancy. R8 ran 254 blocks x 512 = 1 block/CU = 8 waves/CU (2/SIMD);
// the kernel is at <=5% of both VALU and HBM rooflines, so it is latency-bound —
// per-block setup (A/B1/B2 behind __syncthreads) and dep-chain bubbles are exposed.
// Now 2 patches/thread -> 260096 threads = 508 blocks x 512 = 2 blocks/CU,
// 16 waves/CU (4/SIMD via __launch_bounds__), so one block's eval hides the other
// block's setup. Setup phases are byte-identical to R8; per-patch Horner math is
// bit-identical (absmax must stay 0.00390625).
//   Phase A : wave 0, 4 lanes per U-column (shfl_xor cross-lane gates) -> Ut in LDS
//   Phase B1: M_w = I - 2*sum_{k:bit set} conj(U[k][j])U[k][i]  (unitarity, 8 terms)
//   Phase B2: 324 coefficient traces -> sW[81] (float4 over output wires)
//   Phase C : eval, 2 patches/thread, inside-out (Horner) contraction:
//             d = q0 + y3*q1 + c3*q2 per base-3 digit level; float4 lanes are the
//             4 output wires, so the final accumulator is the output vector.
// Wire q <-> state bit (8>>q).  Block=512, grid=508 (exactly 260096 threads).

#define HH 128
#define WW 128
#define HO 127
#define WO 127
#define BB 32
#define JSLOTS 64   // 2-column thread-slots per output row
#define TPB 512

typedef float v4f __attribute__((ext_vector_type(4)));

__global__ __launch_bounds__(TPB, 4) void qconv_fused(
    const float* __restrict__ x, const float* __restrict__ prm,
    float* __restrict__ out) {
    __shared__ float Utr[16][20];   // Ut[j][k] = U[k][j]; stride 20: aligned, conflict-free
    __shared__ float Uti[16][20];
    __shared__ float Mr[4][16][17]; // M_w[j][i], padded
    __shared__ float Mi[4][16][17];
    __shared__ v4f sW[81];          // sW[p] = c_{*,P}, lanes = output wires

    const int tid = threadIdx.x;

    // ---- Phase A: U columns, 4 lanes per column (wave 0) ----
    if (tid < 64) {
        const int c = tid >> 2;   // column j
        const int g = tid & 3;    // amp group: amps 4g..4g+3 (m = amp&3)
        float re[4], im[4];
#pragma unroll
        for (int m = 0; m < 4; ++m) { re[m] = (4 * g + m == c) ? 1.f : 0.f; im[m] = 0.f; }

#pragma unroll
        for (int l = 0; l < 2; ++l) {
            const float* p = prm + l * 8;
            // --- wire0: RX (mask8 -> cross lane^2), RZ (bit = g>>1) ---
            { float s, cc; __sincosf(p[0] * 0.5f, &s, &cc);
              float pr[4], pi[4];
#pragma unroll
              for (int m = 0; m < 4; ++m) { pr[m] = __shfl_xor(re[m], 2); pi[m] = __shfl_xor(im[m], 2); }
#pragma unroll
              for (int m = 0; m < 4; ++m) { re[m] = fmaf(cc, re[m], s * pi[m]); im[m] = fmaf(cc, im[m], -s * pr[m]); } }
            { float sp, cp; __sincosf(p[1] * 0.5f, &sp, &cp);
              const float sg = (g & 2) ? sp : -sp;
#pragma unroll
              for (int m = 0; m < 4; ++m) { float r = re[m], q = im[m];
                  re[m] = fmaf(r, cp, -q * sg); im[m] = fmaf(q, cp, r * sg); } }
            // --- wire1: RX (mask4 -> cross lane^1), RZ (bit = g&1) ---
            { float s, cc; __sincosf(p[2] * 0.5f, &s, &cc);
              float pr[4], pi[4];
#pragma unroll
              for (int m = 0; m < 4; ++m) { pr[m] = __shfl_xor(re[m], 1); pi[m] = __shfl_xor(im[m], 1); }
#pragma unroll
              for (int m = 0; m < 4; ++m) { re[m] = fmaf(cc, re[m], s * pi[m]); im[m] = fmaf(cc, im[m], -s * pr[m]); } }
            { float sp, cp; __sincosf(p[3] * 0.5f, &sp, &cp);
              const float sg = (g & 1) ? sp : -sp;
#pragma unroll
              for (int m = 0; m < 4; ++m) { float r = re[m], q = im[m];
                  re[m] = fmaf(r, cp, -q * sg); im[m] = fmaf(q, cp, r * sg); } }
            // --- wire2: RX (mask2 -> local m^2), RZ (bit = m>>1) ---
            { float s, cc; __sincosf(p[4] * 0.5f, &s, &cc);
              float r0 = re[0], r1 = re[1], r2 = re[2], r3 = re[3];
              float i0 = im[0], i1 = im[1], i2 = im[2], i3 = im[3];
              re[0] = fmaf(cc, r0, s * i2); im[0] = fmaf(cc, i0, -s * r2);
              re[1] = fmaf(cc, r1, s * i3); im[1] = fmaf(cc, i1, -s * r3);
              re[2] = fmaf(cc, r2, s * i0); im[2] = fmaf(cc, i2, -s * r0);
              re[3] = fmaf(cc, r3, s * i1); im[3] = fmaf(cc, i3, -s * r1); }
            { float sp, cp; __sincosf(p[5] * 0.5f, &sp, &cp);
              float r, q;
              r = re[0]; q = im[0]; re[0] = fmaf(r, cp,  q * sp); im[0] = fmaf(q, cp, -r * sp);
              r = re[1]; q = im[1]; re[1] = fmaf(r, cp,  q * sp); im[1] = fmaf(q, cp, -r * sp);
              r = re[2]; q = im[2]; re[2] = fmaf(r, cp, -q * sp); im[2] = fmaf(q, cp,  r * sp);
              r = re[3]; q = im[3]; re[3] = fmaf(r, cp, -q * sp); im[3] = fmaf(q, cp,  r * sp); }
            // --- wire3: RX (mask1 -> local m^1), RZ (bit = m&1) ---
            { float s, cc; __sincosf(p[6] * 0.5f, &s, &cc);
              float r0 = re[0], r1 = re[1], r2 = re[2], r3 = re[3];
              float i0 = im[0], i1 = im[1], i2 = im[2], i3 = im[3];
              re[0] = fmaf(cc, r0, s * i1); im[0] = fmaf(cc, i0, -s * r1);
              re[1] = fmaf(cc, r1, s * i0); im[1] = fmaf(cc, i1, -s * r0);
              re[2] = fmaf(cc, r2, s * i3); im[2] = fmaf(cc, i2, -s * r3);
              re[3] = fmaf(cc, r3, s * i2); im[3] = fmaf(cc, i3, -s * r2); }
            { float sp, cp; __sincosf(p[7] * 0.5f, &sp, &cp);
              float r, q;
              r = re[0]; q = im[0]; re[0] = fmaf(r, cp,  q * sp); im[0] = fmaf(q, cp, -r * sp);
              r = re[1]; q = im[1]; re[1] = fmaf(r, cp, -q * sp); im[1] = fmaf(q, cp,  r * sp);
              r = re[2]; q = im[2]; re[2] = fmaf(r, cp,  q * sp); im[2] = fmaf(q, cp, -r * sp);
              r = re[3]; q = im[3]; re[3] = fmaf(r, cp, -q * sp); im[3] = fmaf(q, cp,  r * sp); }
            // --- CNOT(ctrl bit2 = g&1, tgt bit3): lanes with g&1 take lane^2's regs ---
#pragma unroll
            for (int m = 0; m < 4; ++m) {
                float pr = __shfl_xor(re[m], 2), pi = __shfl_xor(im[m], 2);
                if (g & 1) { re[m] = pr; im[m] = pi; }
            }
            // --- CNOT(ctrl bit1 = m>>1, tgt bit2): m=2,3 exchange across lane^1 ---
            re[2] = __shfl_xor(re[2], 1); im[2] = __shfl_xor(im[2], 1);
            re[3] = __shfl_xor(re[3], 1); im[3] = __shfl_xor(im[3], 1);
            // --- CNOT(ctrl bit0 = m&1, tgt bit1): local swap amps 1<->3 ---
            { float t;
              t = re[1]; re[1] = re[3]; re[3] = t;
              t = im[1]; im[1] = im[3]; im[3] = t; }
        }
        *(float4*)&Utr[c][4 * g] = make_float4(re[0], re[1], re[2], re[3]);
        *(float4*)&Uti[c][4 * g] = make_float4(im[0], im[1], im[2], im[3]);
    }
    __syncthreads();

    // ---- Phase B1: M_w[j][i] = delta_ji - 2*sum_{k: k&zbit} conj(U[k][j]) U[k][i] ----
    {
        const int e0 = tid * 2;            // 1024 entries, 2 per thread (i0 even)
        const int w = e0 >> 8;
        const int j = (e0 >> 4) & 15;
        const int i0 = e0 & 15;
        const int zbit = 8 >> w;
        const int lowmask = zbit - 1;
        float sr0 = 0.f, si0 = 0.f, sr1 = 0.f, si1 = 0.f;
#pragma unroll
        for (int t = 0; t < 8; ++t) {
            const int k = ((t & ~lowmask) << 1) | zbit | (t & lowmask);
            const float ar = Utr[j][k],      ai = Uti[j][k];
            const float br0 = Utr[i0][k],    bi0 = Uti[i0][k];
            const float br1 = Utr[i0 + 1][k], bi1 = Uti[i0 + 1][k];
            sr0 += fmaf(ar, br0, ai * bi0);  si0 += fmaf(ar, bi0, -ai * br0);
            sr1 += fmaf(ar, br1, ai * bi1);  si1 += fmaf(ar, bi1, -ai * br1);
        }
        Mr[w][j][i0]     = ((j == i0)     ? 1.f : 0.f) - 2.f * sr0;
        Mi[w][j][i0]     = -2.f * si0;
        Mr[w][j][i0 + 1] = ((j == i0 + 1) ? 1.f : 0.f) - 2.f * sr1;
        Mi[w][j][i0 + 1] = -2.f * si1;
    }
    __syncthreads();

    // ---- Phase B2: coefficient traces (324, one per thread) ----
    if (tid < 324) {
        const int w = tid / 81;
        int p = tid % 81;
        const int pidx = p;
        const int t3 = p % 3; p /= 3;
        const int t2 = p % 3; p /= 3;
        const int t1 = p % 3;
        const int t0 = p / 3;
        const int f = (t0 == 1 ? 8 : 0) | (t1 == 1 ? 4 : 0) |
                      (t2 == 1 ? 2 : 0) | (t3 == 1 ? 1 : 0);
        float acc = 0.f;
        for (int i = 0; i < 16; ++i) {
            // phase = P[i][i^f]; Z: diag(1,-1); Y[0][1]=-i, Y[1][0]=+i.
            float pr = 1.f, pi = 0.f;
            int ib;
            ib = (i >> 3) & 1;
            if (t0 == 2) { if (ib) { pr = -pr; pi = -pi; } }
            else if (t0 == 1) { float tt = pr; if (ib) { pr = -pi; pi = tt; } else { pr = pi; pi = -tt; } }
            ib = (i >> 2) & 1;
            if (t1 == 2) { if (ib) { pr = -pr; pi = -pi; } }
            else if (t1 == 1) { float tt = pr; if (ib) { pr = -pi; pi = tt; } else { pr = pi; pi = -tt; } }
            ib = (i >> 1) & 1;
            if (t2 == 2) { if (ib) { pr = -pr; pi = -pi; } }
            else if (t2 == 1) { float tt = pr; if (ib) { pr = -pi; pi = tt; } else { pr = pi; pi = -tt; } }
            ib = i & 1;
            if (t3 == 2) { if (ib) { pr = -pr; pi = -pi; } }
            else if (t3 == 1) { float tt = pr; if (ib) { pr = -pi; pi = tt; } else { pr = pi; pi = -tt; } }
            const int j = i ^ f;
            acc += pr * Mr[w][j][i] - pi * Mi[w][j][i];
        }
        ((float*)sW)[pidx * 4 + w] = acc * (1.0f / 16.0f);
    }
    __syncthreads();

    // ---- Phase C: eval, 2 consecutive output columns per thread, Horner ----
    const int tid_g = blockIdx.x * TPB + tid;   // grid is exactly 508*512
    const int slot = tid_g & (JSLOTS - 1);
    const int t = tid_g >> 6;
    const int i = t % HO;
    const int b = t / HO;
    const int j0 = slot * 2;   // 8B-aligned

    const float* row0 = x + ((size_t)b * HH + i) * WW + j0;
    const float* row1 = row0 + WW;
    const float2 v0 = *(const float2*)row0;
    const float2 v1 = *(const float2*)row1;
    const bool has3 = (j0 + 2 < WW);
    const float x02 = has3 ? row0[2] : 0.f;
    const float x12 = has3 ? row1[2] : 0.f;
    const float r0[3] = {v0.x, v0.y, x02};
    const float r1[3] = {v1.x, v1.y, x12};

    // 6 unique angles -> 6 sincos
    float s0[3], c0[3], s1[3], c1[3];
#pragma unroll
    for (int u = 0; u < 3; ++u) {
        __sincosf(r0[u], &s0[u], &c0[u]);
        __sincosf(r1[u], &s1[u], &c1[u]);
    }
    // patch pp wires: w0 angle r0[pp], w1 r0[pp+1], w2 r1[pp], w3 r1[pp+1]
    float y0v[2], c0v[2], y1v[2], c1v[2], y2v[2], c2v[2], y3v[2], c3v[2];
#pragma unroll
    for (int pp = 0; pp < 2; ++pp) {
        y0v[pp] = -s0[pp];     c0v[pp] = c0[pp];
        y1v[pp] = -s0[pp + 1]; c1v[pp] = c0[pp + 1];
        y2v[pp] = -s1[pp];     c2v[pp] = c1[pp];
        y3v[pp] = -s1[pp + 1]; c3v[pp] = c1[pp + 1];
    }

    v4f acc0[2];
#pragma unroll
    for (int p0 = 0; p0 < 3; ++p0) {
        v4f acc1[2];
#pragma unroll
        for (int p1 = 0; p1 < 3; ++p1) {
            v4f acc2[2];
#pragma unroll
            for (int p2 = 0; p2 < 3; ++p2) {
                const int base = ((p0 * 3 + p1) * 3 + p2) * 3;
                const v4f q0 = sW[base], q1 = sW[base + 1], q2 = sW[base + 2];
#pragma unroll
                for (int pp = 0; pp < 2; ++pp) {
                    v4f d = q0 + y3v[pp] * q1 + c3v[pp] * q2;  // 2 v4 fma
                    if (p2 == 0)      acc2[pp] = d;
                    else if (p2 == 1) acc2[pp] += y2v[pp] * d;
                    else              acc2[pp] += c2v[pp] * d;
                }
            }
#pragma unroll
            for (int pp = 0; pp < 2; ++pp) {
                if (p1 == 0)      acc1[pp] = acc2[pp];
                else if (p1 == 1) acc1[pp] += y1v[pp] * acc2[pp];
                else              acc1[pp] += c1v[pp] * acc2[pp];
            }
        }
#pragma unroll
        for (int pp = 0; pp < 2; ++pp) {
            if (p0 == 0)      acc0[pp] = acc1[pp];
            else if (p0 == 1) acc0[pp] += y0v[pp] * acc1[pp];
            else              acc0[pp] += c0v[pp] * acc1[pp];
        }
    }

    const int npatch = (j0 + 2 <= WO) ? 2 : 1;  // slot 63 -> 1
    float* obase = out + (((size_t)b * 4) * HO + (size_t)i) * WO + j0;
#pragma unroll
    for (int w = 0; w < 4; ++w) {
        float* o = obase + (size_t)w * HO * WO;
        for (int pp = 0; pp < npatch; ++pp) o[pp] = acc0[pp][w];
    }
}

extern "C" void kernel_launch(void* const* d_in, const int* in_sizes, int n_in,
                              void* d_out, int out_size, void* d_ws, size_t ws_size,
                              hipStream_t stream) {
    const float* x = (const float*)d_in[0];
    const float* prm = (const float*)d_in[1];
    float* out = (float*)d_out;

    const int total_threads = BB * HO * JSLOTS;  // 260096 = 508 * 512 exactly
    const int blocks = total_threads / TPB;
    qconv_fused<<<blocks, TPB, 0, stream>>>(x, prm, out);
}